// Round 13
// baseline (1037.576 us; speedup 1.0000x reference)
//
#include <hip/hip_runtime.h>
#include <hip/hip_bf16.h>
#include <stdint.h>

#define HH 128
#define WW 128
#define NIMG 32
#define CH 16
#define TX 32            // tile width
#define TY 8             // tile height
// gated planes: 34x10 (1-px halo), raw ch0 plane: 36x12 (2-px halo)
#define GST 34           // gated plane row stride
#define GLA 340          // gated plane size (34*10)
#define RST 36           // raw plane row stride
#define RLA 432          // raw plane size (36*12)
#define RAW_OFF (16 * GLA)   // raw plane offset in floats (5440)
#define NUM_ITER 30
#define THR 0.1f
#define HWSZ (HH * WW)

// PSTR=48: rows are 96 B -> 16-B aligned (b128 frag ops preserved) AND zero
// pad columns. SMEM = 256*48*2 = 24576 B -> 6 blocks/CU (160K/24576 = 6.5).
// Closes the {alignment x residency} matrix: (52,6)=R10, (56,5)=R12, (48,6)=R13.
// Bank cost: B-read row stride 24 dw -> px, px+4, px+8, px+12 share a bank
// cluster = 4-way on ~16 b128 ops/wave ~= +100 cyc/wave (m136 arithmetic) --
// accepted against +1 resident block.
#define PSTR 48
#define SMEM_BYTES (256 * PSTR * 2)    // 24576 B

typedef __attribute__((ext_vector_type(8))) short bf16x8;
typedef __attribute__((ext_vector_type(4))) float f32x4;
typedef __attribute__((ext_vector_type(4))) short sh4;

// hardware RNE f32->bf16
__device__ __forceinline__ unsigned short f2bf(float x) {
    return __builtin_bit_cast(unsigned short, __float2bfloat16(x));
}
__device__ __forceinline__ float bf2f(unsigned short h) {
    union { unsigned u; float f; } v; v.u = ((unsigned)h) << 16; return v.f;
}
// direct 16-B vector load (caller guarantees 16-B alignment)
__device__ __forceinline__ bf16x8 lb8(const unsigned short* p) {
    return *(const bf16x8*)p;
}
// 9-point max as v_max3-fusable triples
__device__ __forceinline__ float max9(const float* p, int idx, int stride) {
    float a = fmaxf(fmaxf(p[idx - stride - 1], p[idx - stride]), p[idx - stride + 1]);
    float b = fmaxf(fmaxf(p[idx - 1],          p[idx]),          p[idx + 1]);
    float c = fmaxf(fmaxf(p[idx + stride - 1], p[idx + stride]), p[idx + stride + 1]);
    return fmaxf(fmaxf(a, b), c);
}

// ---------------- weight prepack: bf16 hi/lo split, row-major ----
__global__ void prepack(const float* __restrict__ w1, const float* __restrict__ w2,
                        unsigned short* __restrict__ w1h, unsigned short* __restrict__ w1l,
                        unsigned short* __restrict__ w2h, unsigned short* __restrict__ w2l) {
    int i = threadIdx.x;
    for (int k = i; k < 48 * 48; k += 256) {
        float f = w1[k];
        unsigned short h = f2bf(f);
        w1h[k] = h;
        w1l[k] = f2bf(f - bf2f(h));
    }
    for (int k = i; k < 16 * 48; k += 256) {
        float f = w2[k];
        unsigned short h = f2bf(f);
        w2h[k] = h;
        w2l[k] = f2bf(f - bf2f(h));
    }
}

// perception: p[0..15]=center, p[16..31]=sobel-x, p[32..47]=sobel-y
// gated planes, stride GST=34, plane size GLA=340
__device__ __forceinline__ void perception_at(const float* cs, int base, float* p) {
#pragma unroll
    for (int c = 0; c < CH; ++c) {
        const float* cc = cs + c * GLA;
        float c00 = cc[base - GST - 1], c01 = cc[base - GST], c02 = cc[base - GST + 1];
        float c10 = cc[base - 1],       c11 = cc[base],       c12 = cc[base + 1];
        float c20 = cc[base + GST - 1], c21 = cc[base + GST], c22 = cc[base + GST + 1];
        p[c]      = c11;
        p[16 + c] = (c02 - c00 + 2.0f * (c12 - c10) + c22 - c20) * 0.125f;
        p[32 + c] = (c20 - c00 + 2.0f * (c21 - c01) + c22 - c02) * 0.125f;
    }
}

// ---------------- one fused CA step (MFMA matmuls, R13) ----------------
// R13 vs R12 (single change): PSTR 56->48. Keeps the b128 fragment ops
// (rows stay 16-B aligned) and regains 6 blocks/CU (SMEM 24576 B).
// Everything else identical. Math bit-identical; absmax must stay 0.0625.
__global__ __launch_bounds__(256, 6) void step_kernel(
    const float* __restrict__ inp, const float* __restrict__ cin,
    float* __restrict__ cout,
    const uint8_t* __restrict__ pre_in, uint8_t* __restrict__ pre_out,
    const unsigned short* __restrict__ w1h_, const unsigned short* __restrict__ w1l_,
    const unsigned short* __restrict__ w2h_, const unsigned short* __restrict__ w2l_,
    int gate, int first) {

    __shared__ __align__(16) char smem[SMEM_BYTES];
    float* cs = (float*)smem;                       // 16 gated planes + raw plane
    unsigned short* Ph = (unsigned short*)smem;     // [256][PSTR] bf16 (overlays cs)

    const int tid = threadIdx.x;
    const int tx2 = tid & 31, ty2 = tid >> 5;       // pixel within 32x8 tile
    const int lane = tid & 63;
    const int wv = tid >> 6;            // wave id: pixels [64*wv, 64*wv+64) = rows 2wv,2wv+1
    const int px = lane & 15;           // col within 16-tile
    const int kc = lane >> 4;           // k-chunk id (0..3)

    // ---- XCD-aware decode: wgid%8 = XCD; each XCD owns 4 whole images ----
    const int wgid = blockIdx.x;
    const int xcd = wgid & 7;
    const int s   = wgid >> 3;              // 0..255 per XCD
    const int n   = (xcd << 2) + (s >> 6);  // image
    const int t_  = s & 63;                 // tile within image (4x16)
    const int bx = (t_ & 3) * TX;
    const int by = (t_ >> 2) * TY;

    const float* cbase = cin + (size_t)n * CH * HWSZ;
    const float* ibase = inp + (size_t)n * 10 * HWSZ;
    const uint8_t* pbase = pre_in + (size_t)n * HWSZ;

    // ---- hoisted coords: full 36x12 positions (raw ch0), two per thread ----
    const int lyA = tid / 36, lxA = tid % 36;
    const int gyA = by + lyA - 2, gxA = bx + lxA - 2;
    const bool okA = ((unsigned)gyA < HH) && ((unsigned)gxA < WW);
    const int offA = gyA * WW + gxA;

    const int rB = tid + 256;                  // valid when tid < 176 (432 total)
    const int lyB = rB / 36, lxB = rB % 36;
    const int gyB = by + lyB - 2, gxB = bx + lxB - 2;
    const bool okB = ((unsigned)gyB < HH) && ((unsigned)gxB < WW);
    const int offB = gyB * WW + gxB;
    const bool hasA2 = (tid < 176);

    // ---- hoisted coords: 34x10 gate-region positions, two per thread ----
    const int j0 = tid;                        // always < 340
    const int jy0 = j0 / 34, jx0 = j0 % 34;
    const int gy0 = by + jy0 - 1, gx0 = bx + jx0 - 1;
    const bool ok0 = ((unsigned)gy0 < HH) && ((unsigned)gx0 < WW);
    const int goff0 = gy0 * WW + gx0;
    const int rpos0 = (jy0 + 1) * RST + (jx0 + 1);   // raw-plane pos

    const int j1 = tid + 256;                  // valid when tid < 84 (340 total)
    const int jy1 = j1 / 34, jx1 = j1 % 34;
    const int gy1 = by + jy1 - 1, gx1 = bx + jx1 - 1;
    const bool ok1 = ((unsigned)gy1 < HH) && ((unsigned)gx1 < WW);
    const int goff1 = gy1 * WW + gx1;
    const int rpos1 = (jy1 + 1) * RST + (jx1 + 1);
    const bool hasB = (tid < 84);

    // ---- A: stage raw ch0 (raw plane) AND pre-issue all global loads ----
    // first=1: read from inp with the init mapping (ch0 = 1-inp0).
    if (first) {
        cs[RAW_OFF + tid] = okA ? 1.0f - ibase[offA] : 0.0f;
        if (hasA2) cs[RAW_OFF + rB] = okB ? 1.0f - ibase[offB] : 0.0f;
    } else {
        cs[RAW_OFF + tid] = okA ? cbase[offA] : 0.0f;
        if (hasA2) cs[RAW_OFF + rB] = okB ? cbase[offB] : 0.0f;
    }

    float st0[CH - 1];
    float st1[CH - 1];
    int pv0 = 1, pv1 = 1;
    if (first) {
#pragma unroll
        for (int c = 1; c < CH; ++c)
            st0[c - 1] = (c <= 10 && ok0) ? ibase[(c - 1) * HWSZ + goff0] : 0.0f;
        if (hasB) {
#pragma unroll
            for (int c = 1; c < CH; ++c)
                st1[c - 1] = (c <= 10 && ok1) ? ibase[(c - 1) * HWSZ + goff1] : 0.0f;
        }
    } else {
        {
            const float* gp = cbase + goff0;
#pragma unroll
            for (int c = 1; c < CH; ++c) st0[c - 1] = ok0 ? gp[c * HWSZ] : 0.0f;
        }
        if (gate) pv0 = ok0 ? (int)pbase[goff0] : 0;
        if (hasB) {
            const float* gp = cbase + goff1;
#pragma unroll
            for (int c = 1; c < CH; ++c) st1[c - 1] = ok1 ? gp[c * HWSZ] : 0.0f;
            if (gate) pv1 = ok1 ? (int)pbase[goff1] : 0;
        }
    }
    __syncthreads();   // sync1

    // ---- B+C fused: gate from raw plane; gated writes to planes 0..15
    //      (gated plane index == gate-region index j) ----
    {
        const float* rp = cs + RAW_OFF;
        float pm = max9(rp, rpos0, RST);
        float g0 = 1.0f;
        if (gate) g0 = (pv0 && pm > THR) ? 1.0f : 0.0f;
        cs[j0] = rp[rpos0] * g0;
#pragma unroll
        for (int c = 1; c < CH; ++c) cs[c * GLA + j0] = st0[c - 1] * g0;
    }
    if (hasB) {
        const float* rp = cs + RAW_OFF;
        float pm = max9(rp, rpos1, RST);
        float g1 = 1.0f;
        if (gate) g1 = (pv1 && pm > THR) ? 1.0f : 0.0f;
        cs[j1] = rp[rpos1] * g1;
#pragma unroll
        for (int c = 1; c < CH; ++c) cs[c * GLA + j1] = st1[c - 1] * g1;
    }
    __syncthreads();   // sync2

    // ---- D1: pre(i) bits + per-thread perception + residual grab (reads cs) ----
    const int base = (ty2 + 1) * GST + (tx2 + 1);
    {
        float pm = max9(cs, base, GST);
        pre_out[(size_t)n * HWSZ + (size_t)(by + ty2) * WW + (bx + tx2)] = (pm > THR) ? 1 : 0;
    }

    float p[48];
    perception_at(cs, base, p);

    // residual for this lane's D5 output assignment: pixel pix=64wv+16t+px,
    // channel 4kc+r -- gated fp32 state from cs, read before the Ph overlay.
    float res[4][4];
#pragma unroll
    for (int t = 0; t < 4; ++t) {
        const int pix = 64 * wv + 16 * t + px;
        const int lp = ((pix >> 5) + 1) * GST + ((pix & 31) + 1);
#pragma unroll
        for (int r = 0; r < 4; ++r)
            res[t][r] = cs[(4 * kc + r) * GLA + lp];
    }
    __syncthreads();   // sync3: all cs reads done; Ph may now overlay cs

    // ---- D2: p -> bf16 hi into LDS, 6x b128 writes (rows 16-B aligned) ----
    {
        unsigned short* hrow = Ph + tid * PSTR;
#pragma unroll
        for (int j = 0; j < 6; ++j) {
            bf16x8 hv;
#pragma unroll
            for (int e = 0; e < 8; ++e)
                hv[e] = (short)f2bf(p[8 * j + e]);
            *(bf16x8*)(hrow + 8 * j) = hv;
        }
    }
    // no barrier: D3 B-reads are wave-private rows, DS pipe in-order per wave

    // ---- D3: h = relu(w1 x P) via MFMA (2-product: (w1h+w1l) x Phi) ----
    const bf16x8 zero8 = (bf16x8)0;

    f32x4 acc[3][4];
#pragma unroll
    for (int m = 0; m < 3; ++m)
#pragma unroll
        for (int t = 0; t < 4; ++t) acc[m][t] = 0.0f;

#pragma unroll
    for (int m = 0; m < 3; ++m) {
        const unsigned short* ah = w1h_ + (16 * m + px) * 48;
        const unsigned short* al = w1l_ + (16 * m + px) * 48;
        bf16x8 Ah1 = lb8(ah + 8 * kc);
        bf16x8 Ah2 = lb8(ah + 32 + 8 * kc);  // padded buf; garbage for kc>=2 ok (B=0)
        bf16x8 Al1 = lb8(al + 8 * kc);
        bf16x8 Al2 = lb8(al + 32 + 8 * kc);
#pragma unroll
        for (int t = 0; t < 4; ++t) {
            const int pix = 64 * wv + 16 * t + px;
            const unsigned short* bh = Ph + pix * PSTR;
            bf16x8 Bh1 = lb8(bh + 8 * kc);
            bf16x8 Bh2 = (kc < 2) ? lb8(bh + 32 + 8 * kc) : zero8;
            f32x4 a = acc[m][t];
            a = __builtin_amdgcn_mfma_f32_16x16x32_bf16(Al1, Bh1, a, 0, 0, 0);
            a = __builtin_amdgcn_mfma_f32_16x16x32_bf16(Al2, Bh2, a, 0, 0, 0);
            a = __builtin_amdgcn_mfma_f32_16x16x32_bf16(Ah1, Bh1, a, 0, 0, 0);
            a = __builtin_amdgcn_mfma_f32_16x16x32_bf16(Ah2, Bh2, a, 0, 0, 0);
            acc[m][t] = a;
        }
    }
    // no barrier: D4 writes the same wave-private rows D3 just read

    // ---- D4: h = relu(acc) -> bf16, overlaying Ph. lane holds q=16m+4kc+r ----
#pragma unroll
    for (int t = 0; t < 4; ++t) {
        const int pix = 64 * wv + 16 * t + px;
        unsigned short* hrow = Ph + pix * PSTR;
#pragma unroll
        for (int m = 0; m < 3; ++m) {
            f32x4 a = acc[m][t];
            sh4 hv;
            hv.x = (short)f2bf(fmaxf(a[0], 0.0f));
            hv.y = (short)f2bf(fmaxf(a[1], 0.0f));
            hv.z = (short)f2bf(fmaxf(a[2], 0.0f));
            hv.w = (short)f2bf(fmaxf(a[3], 0.0f));
            *(sh4*)(hrow + 16 * m + 4 * kc) = hv;
        }
    }
    // no barrier: D5 reads the same wave-private rows

    // ---- D5: cur = (w2h+w2l) x H + res; plain scalar stores ----
    {
        const unsigned short* ah = w2h_ + px * 48;
        const unsigned short* al = w2l_ + px * 48;
        bf16x8 A2h1 = lb8(ah + 8 * kc);
        bf16x8 A2h2 = lb8(ah + 32 + 8 * kc);
        bf16x8 A2l1 = lb8(al + 8 * kc);
        bf16x8 A2l2 = lb8(al + 32 + 8 * kc);

        f32x4 q[4];
#pragma unroll
        for (int t = 0; t < 4; ++t) q[t] = 0.0f;
#pragma unroll
        for (int t = 0; t < 4; ++t) {
            const int pix = 64 * wv + 16 * t + px;
            const unsigned short* bh = Ph + pix * PSTR;
            bf16x8 B1 = lb8(bh + 8 * kc);
            bf16x8 B2 = (kc < 2) ? lb8(bh + 32 + 8 * kc) : zero8;
            f32x4 a = q[t];
            a = __builtin_amdgcn_mfma_f32_16x16x32_bf16(A2l1, B1, a, 0, 0, 0);
            a = __builtin_amdgcn_mfma_f32_16x16x32_bf16(A2l2, B2, a, 0, 0, 0);
            a = __builtin_amdgcn_mfma_f32_16x16x32_bf16(A2h1, B1, a, 0, 0, 0);
            a = __builtin_amdgcn_mfma_f32_16x16x32_bf16(A2h2, B2, a, 0, 0, 0);
            q[t] = a;
        }

        float* ob = cout + (size_t)n * CH * HWSZ;
#pragma unroll
        for (int t = 0; t < 4; ++t) {
            const int pix = 64 * wv + 16 * t + px;
            const int rowoff = (by + (pix >> 5)) * WW + bx + (pix & 31);
#pragma unroll
            for (int r = 0; r < 4; ++r)
                ob[(size_t)(4 * kc + r) * HWSZ + rowoff] = q[t][r] + res[t][r];
        }
    }
}

// ---------------- final: apply gate(30), emit channels 1..10 ----------------
__global__ __launch_bounds__(256) void final_kernel(
    const float* __restrict__ cur, const uint8_t* __restrict__ pre,
    float* __restrict__ out) {
    int i = blockIdx.x * 256 + threadIdx.x;        // over NIMG*H*W
    if (i >= NIMG * HWSZ) return;
    int x = i % WW, y = (i / WW) % HH, n = i / HWSZ;
    const float* c0 = cur + (size_t)n * CH * HWSZ;
    float pm = -1e30f;
    for (int dy = -1; dy <= 1; ++dy) {
        int yy = y + dy;
        if ((unsigned)yy >= HH) continue;
        for (int dx = -1; dx <= 1; ++dx) {
            int xx = x + dx;
            if ((unsigned)xx >= WW) continue;
            pm = fmaxf(pm, c0[yy * WW + xx]);
        }
    }
    const bool alive = pre[i] && (pm > THR);
    float* ob = out + (size_t)n * 10 * HWSZ + y * WW + x;
#pragma unroll
    for (int k = 1; k <= 10; ++k)
        ob[(k - 1) * HWSZ] = alive ? c0[k * HWSZ + y * WW + x] : 0.0f;
}

extern "C" void kernel_launch(void* const* d_in, const int* in_sizes, int n_in,
                              void* d_out, int out_size, void* d_ws, size_t ws_size,
                              hipStream_t stream) {
    const float* inp = (const float*)d_in[0];
    const float* w1  = (const float*)d_in[1];
    const float* w2  = (const float*)d_in[2];
    float* out = (float*)d_out;

    const size_t SE = (size_t)NIMG * CH * HWSZ;    // 8,388,608 floats
    float* bufA = (float*)d_ws;
    float* bufB = bufA + SE;
    uint8_t* bitsA = (uint8_t*)(bufB + SE);
    uint8_t* bitsB = bitsA + (size_t)NIMG * HWSZ;
    // weight fragments (bf16), padded +32 shorts so chunk-2 A reads stay in-bounds
    unsigned short* w1h = (unsigned short*)(bitsB + (size_t)NIMG * HWSZ);
    unsigned short* w1l = w1h + (48 * 48 + 32);
    unsigned short* w2h = w1l + (48 * 48 + 32);
    unsigned short* w2l = w2h + (16 * 48 + 32);

    prepack<<<1, 256, 0, stream>>>(w1, w2, w1h, w1l, w2h, w2l);

    const int nblk = NIMG * (HH / TY) * (WW / TX);   // 2048, 1-D swizzled grid
    float* src = bufB;      // dummy on first iter (first=1 reads inp)
    float* dst = bufA;
    uint8_t* pin = bitsB;   // unused on first iter (gate=0)
    uint8_t* pout = bitsA;
    for (int it = 0; it < NUM_ITER; ++it) {
        step_kernel<<<nblk, 256, 0, stream>>>(inp, src, dst, pin, pout,
                                              w1h, w1l, w2h, w2l,
                                              it == 0 ? 0 : 1, it == 0 ? 1 : 0);
        float* t = src; src = dst; dst = t;
        uint8_t* tb = pin; pin = pout; pout = tb;
    }
    // after loop: src = cur(30), pin = pre(30) bits
    final_kernel<<<(NIMG * HWSZ + 255) / 256, 256, 0, stream>>>(src, pin, out);
}

// Round 14
// 864.023 us; speedup vs baseline: 1.2009x; 1.2009x over previous
//
#include <hip/hip_runtime.h>
#include <hip/hip_bf16.h>
#include <stdint.h>

#define HH 128
#define WW 128
#define NIMG 32
#define CH 16
#define TX 32            // tile width
#define TY 8             // tile height
// gated planes: 34x10 (1-px halo), raw ch0 plane: 36x12 (2-px halo)
#define GST 34           // gated plane row stride
#define GLA 340          // gated plane size (34*10)
#define RST 36           // raw plane row stride
#define RLA 432          // raw plane size (36*12)
#define RAW_OFF (16 * GLA)   // raw plane offset in floats (5440)
#define NUM_ITER 30
#define THR 0.1f
#define HWSZ (HH * WW)

// PSTR=56: rows are 112 B -> 16-B aligned => single ds_read_b128 / ds_write_b128
// fragment ops. Bank pattern: stride 28 dw -> 2-way aliasing only (free, m136).
// SMEM 28672 B -> 5 blocks/CU. CHAMPION CONFIG (R8=871 / R12=884 noise-tied;
// R13 proved 6-blk/4-way-conflict strictly worse: 1037).
#define PSTR 56
#define SMEM_BYTES (256 * PSTR * 2)

typedef __attribute__((ext_vector_type(8))) short bf16x8;
typedef __attribute__((ext_vector_type(4))) float f32x4;
typedef __attribute__((ext_vector_type(4))) short sh4;

// hardware RNE f32->bf16
__device__ __forceinline__ unsigned short f2bf(float x) {
    return __builtin_bit_cast(unsigned short, __float2bfloat16(x));
}
__device__ __forceinline__ float bf2f(unsigned short h) {
    union { unsigned u; float f; } v; v.u = ((unsigned)h) << 16; return v.f;
}
// direct 16-B vector load (caller guarantees 16-B alignment)
__device__ __forceinline__ bf16x8 lb8(const unsigned short* p) {
    return *(const bf16x8*)p;
}
// 9-point max as v_max3-fusable triples
__device__ __forceinline__ float max9(const float* p, int idx, int stride) {
    float a = fmaxf(fmaxf(p[idx - stride - 1], p[idx - stride]), p[idx - stride + 1]);
    float b = fmaxf(fmaxf(p[idx - 1],          p[idx]),          p[idx + 1]);
    float c = fmaxf(fmaxf(p[idx + stride - 1], p[idx + stride]), p[idx + stride + 1]);
    return fmaxf(fmaxf(a, b), c);
}

// ---------------- weight prepack: bf16 hi/lo split, row-major ----
__global__ void prepack(const float* __restrict__ w1, const float* __restrict__ w2,
                        unsigned short* __restrict__ w1h, unsigned short* __restrict__ w1l,
                        unsigned short* __restrict__ w2h, unsigned short* __restrict__ w2l) {
    int i = threadIdx.x;
    for (int k = i; k < 48 * 48; k += 256) {
        float f = w1[k];
        unsigned short h = f2bf(f);
        w1h[k] = h;
        w1l[k] = f2bf(f - bf2f(h));
    }
    for (int k = i; k < 16 * 48; k += 256) {
        float f = w2[k];
        unsigned short h = f2bf(f);
        w2h[k] = h;
        w2l[k] = f2bf(f - bf2f(h));
    }
}

// perception: p[0..15]=center, p[16..31]=sobel-x, p[32..47]=sobel-y
// gated planes, stride GST=34, plane size GLA=340
__device__ __forceinline__ void perception_at(const float* cs, int base, float* p) {
#pragma unroll
    for (int c = 0; c < CH; ++c) {
        const float* cc = cs + c * GLA;
        float c00 = cc[base - GST - 1], c01 = cc[base - GST], c02 = cc[base - GST + 1];
        float c10 = cc[base - 1],       c11 = cc[base],       c12 = cc[base + 1];
        float c20 = cc[base + GST - 1], c21 = cc[base + GST], c22 = cc[base + GST + 1];
        p[c]      = c11;
        p[16 + c] = (c02 - c00 + 2.0f * (c12 - c10) + c22 - c20) * 0.125f;
        p[32 + c] = (c20 - c00 + 2.0f * (c21 - c01) + c22 - c02) * 0.125f;
    }
}

// ---------------- one fused CA step (MFMA matmuls, R14 = R12 champion) ----
// R14: exact revert to R12 (the best-tier config) after R13 closed the
// {alignment x residency} matrix: 5 blk/CU beats 6 in BOTH alignment arms;
// PSTR=56 keeps b128 fragment ops at 2-way (free) bank aliasing.
// All counter-visible mechanisms either exploited (MFMA, tile geometry,
// 3 barriers, pre-issued loads, LDS shave, b128 vectorization, XCD swizzle,
// fused init) or refuted by experiment (store coalescing R7, nt R9, scalar
// R10, interleaved layout R11, 6-blk residency R13). Confirmation run.
__global__ __launch_bounds__(256, 5) void step_kernel(
    const float* __restrict__ inp, const float* __restrict__ cin,
    float* __restrict__ cout,
    const uint8_t* __restrict__ pre_in, uint8_t* __restrict__ pre_out,
    const unsigned short* __restrict__ w1h_, const unsigned short* __restrict__ w1l_,
    const unsigned short* __restrict__ w2h_, const unsigned short* __restrict__ w2l_,
    int gate, int first) {

    __shared__ __align__(16) char smem[SMEM_BYTES];
    float* cs = (float*)smem;                       // 16 gated planes + raw plane
    unsigned short* Ph = (unsigned short*)smem;     // [256][PSTR] bf16 (overlays cs)

    const int tid = threadIdx.x;
    const int tx2 = tid & 31, ty2 = tid >> 5;       // pixel within 32x8 tile
    const int lane = tid & 63;
    const int wv = tid >> 6;            // wave id: pixels [64*wv, 64*wv+64) = rows 2wv,2wv+1
    const int px = lane & 15;           // col within 16-tile
    const int kc = lane >> 4;           // k-chunk id (0..3)

    // ---- XCD-aware decode: wgid%8 = XCD; each XCD owns 4 whole images ----
    const int wgid = blockIdx.x;
    const int xcd = wgid & 7;
    const int s   = wgid >> 3;              // 0..255 per XCD
    const int n   = (xcd << 2) + (s >> 6);  // image
    const int t_  = s & 63;                 // tile within image (4x16)
    const int bx = (t_ & 3) * TX;
    const int by = (t_ >> 2) * TY;

    const float* cbase = cin + (size_t)n * CH * HWSZ;
    const float* ibase = inp + (size_t)n * 10 * HWSZ;
    const uint8_t* pbase = pre_in + (size_t)n * HWSZ;

    // ---- hoisted coords: full 36x12 positions (raw ch0), two per thread ----
    const int lyA = tid / 36, lxA = tid % 36;
    const int gyA = by + lyA - 2, gxA = bx + lxA - 2;
    const bool okA = ((unsigned)gyA < HH) && ((unsigned)gxA < WW);
    const int offA = gyA * WW + gxA;

    const int rB = tid + 256;                  // valid when tid < 176 (432 total)
    const int lyB = rB / 36, lxB = rB % 36;
    const int gyB = by + lyB - 2, gxB = bx + lxB - 2;
    const bool okB = ((unsigned)gyB < HH) && ((unsigned)gxB < WW);
    const int offB = gyB * WW + gxB;
    const bool hasA2 = (tid < 176);

    // ---- hoisted coords: 34x10 gate-region positions, two per thread ----
    const int j0 = tid;                        // always < 340
    const int jy0 = j0 / 34, jx0 = j0 % 34;
    const int gy0 = by + jy0 - 1, gx0 = bx + jx0 - 1;
    const bool ok0 = ((unsigned)gy0 < HH) && ((unsigned)gx0 < WW);
    const int goff0 = gy0 * WW + gx0;
    const int rpos0 = (jy0 + 1) * RST + (jx0 + 1);   // raw-plane pos

    const int j1 = tid + 256;                  // valid when tid < 84 (340 total)
    const int jy1 = j1 / 34, jx1 = j1 % 34;
    const int gy1 = by + jy1 - 1, gx1 = bx + jx1 - 1;
    const bool ok1 = ((unsigned)gy1 < HH) && ((unsigned)gx1 < WW);
    const int goff1 = gy1 * WW + gx1;
    const int rpos1 = (jy1 + 1) * RST + (jx1 + 1);
    const bool hasB = (tid < 84);

    // ---- A: stage raw ch0 (raw plane) AND pre-issue all global loads ----
    // first=1: read from inp with the init mapping (ch0 = 1-inp0).
    if (first) {
        cs[RAW_OFF + tid] = okA ? 1.0f - ibase[offA] : 0.0f;
        if (hasA2) cs[RAW_OFF + rB] = okB ? 1.0f - ibase[offB] : 0.0f;
    } else {
        cs[RAW_OFF + tid] = okA ? cbase[offA] : 0.0f;
        if (hasA2) cs[RAW_OFF + rB] = okB ? cbase[offB] : 0.0f;
    }

    float st0[CH - 1];
    float st1[CH - 1];
    int pv0 = 1, pv1 = 1;
    if (first) {
#pragma unroll
        for (int c = 1; c < CH; ++c)
            st0[c - 1] = (c <= 10 && ok0) ? ibase[(c - 1) * HWSZ + goff0] : 0.0f;
        if (hasB) {
#pragma unroll
            for (int c = 1; c < CH; ++c)
                st1[c - 1] = (c <= 10 && ok1) ? ibase[(c - 1) * HWSZ + goff1] : 0.0f;
        }
    } else {
        {
            const float* gp = cbase + goff0;
#pragma unroll
            for (int c = 1; c < CH; ++c) st0[c - 1] = ok0 ? gp[c * HWSZ] : 0.0f;
        }
        if (gate) pv0 = ok0 ? (int)pbase[goff0] : 0;
        if (hasB) {
            const float* gp = cbase + goff1;
#pragma unroll
            for (int c = 1; c < CH; ++c) st1[c - 1] = ok1 ? gp[c * HWSZ] : 0.0f;
            if (gate) pv1 = ok1 ? (int)pbase[goff1] : 0;
        }
    }
    __syncthreads();   // sync1

    // ---- B+C fused: gate from raw plane; gated writes to planes 0..15
    //      (gated plane index == gate-region index j) ----
    {
        const float* rp = cs + RAW_OFF;
        float pm = max9(rp, rpos0, RST);
        float g0 = 1.0f;
        if (gate) g0 = (pv0 && pm > THR) ? 1.0f : 0.0f;
        cs[j0] = rp[rpos0] * g0;
#pragma unroll
        for (int c = 1; c < CH; ++c) cs[c * GLA + j0] = st0[c - 1] * g0;
    }
    if (hasB) {
        const float* rp = cs + RAW_OFF;
        float pm = max9(rp, rpos1, RST);
        float g1 = 1.0f;
        if (gate) g1 = (pv1 && pm > THR) ? 1.0f : 0.0f;
        cs[j1] = rp[rpos1] * g1;
#pragma unroll
        for (int c = 1; c < CH; ++c) cs[c * GLA + j1] = st1[c - 1] * g1;
    }
    __syncthreads();   // sync2

    // ---- D1: pre(i) bits + per-thread perception + residual grab (reads cs) ----
    const int base = (ty2 + 1) * GST + (tx2 + 1);
    {
        float pm = max9(cs, base, GST);
        pre_out[(size_t)n * HWSZ + (size_t)(by + ty2) * WW + (bx + tx2)] = (pm > THR) ? 1 : 0;
    }

    float p[48];
    perception_at(cs, base, p);

    // residual for this lane's D5 output assignment: pixel pix=64wv+16t+px,
    // channel 4kc+r -- gated fp32 state from cs, read before the Ph overlay.
    float res[4][4];
#pragma unroll
    for (int t = 0; t < 4; ++t) {
        const int pix = 64 * wv + 16 * t + px;
        const int lp = ((pix >> 5) + 1) * GST + ((pix & 31) + 1);
#pragma unroll
        for (int r = 0; r < 4; ++r)
            res[t][r] = cs[(4 * kc + r) * GLA + lp];
    }
    __syncthreads();   // sync3: all cs reads done; Ph may now overlay cs

    // ---- D2: p -> bf16 hi into LDS, 6x b128 writes (rows 16-B aligned) ----
    {
        unsigned short* hrow = Ph + tid * PSTR;
#pragma unroll
        for (int j = 0; j < 6; ++j) {
            bf16x8 hv;
#pragma unroll
            for (int e = 0; e < 8; ++e)
                hv[e] = (short)f2bf(p[8 * j + e]);
            *(bf16x8*)(hrow + 8 * j) = hv;
        }
    }
    // no barrier: D3 B-reads are wave-private rows, DS pipe in-order per wave

    // ---- D3: h = relu(w1 x P) via MFMA (2-product: (w1h+w1l) x Phi) ----
    const bf16x8 zero8 = (bf16x8)0;

    f32x4 acc[3][4];
#pragma unroll
    for (int m = 0; m < 3; ++m)
#pragma unroll
        for (int t = 0; t < 4; ++t) acc[m][t] = 0.0f;

#pragma unroll
    for (int m = 0; m < 3; ++m) {
        const unsigned short* ah = w1h_ + (16 * m + px) * 48;
        const unsigned short* al = w1l_ + (16 * m + px) * 48;
        bf16x8 Ah1 = lb8(ah + 8 * kc);
        bf16x8 Ah2 = lb8(ah + 32 + 8 * kc);  // padded buf; garbage for kc>=2 ok (B=0)
        bf16x8 Al1 = lb8(al + 8 * kc);
        bf16x8 Al2 = lb8(al + 32 + 8 * kc);
#pragma unroll
        for (int t = 0; t < 4; ++t) {
            const int pix = 64 * wv + 16 * t + px;
            const unsigned short* bh = Ph + pix * PSTR;
            bf16x8 Bh1 = lb8(bh + 8 * kc);
            bf16x8 Bh2 = (kc < 2) ? lb8(bh + 32 + 8 * kc) : zero8;
            f32x4 a = acc[m][t];
            a = __builtin_amdgcn_mfma_f32_16x16x32_bf16(Al1, Bh1, a, 0, 0, 0);
            a = __builtin_amdgcn_mfma_f32_16x16x32_bf16(Al2, Bh2, a, 0, 0, 0);
            a = __builtin_amdgcn_mfma_f32_16x16x32_bf16(Ah1, Bh1, a, 0, 0, 0);
            a = __builtin_amdgcn_mfma_f32_16x16x32_bf16(Ah2, Bh2, a, 0, 0, 0);
            acc[m][t] = a;
        }
    }
    // no barrier: D4 writes the same wave-private rows D3 just read

    // ---- D4: h = relu(acc) -> bf16, overlaying Ph. lane holds q=16m+4kc+r ----
#pragma unroll
    for (int t = 0; t < 4; ++t) {
        const int pix = 64 * wv + 16 * t + px;
        unsigned short* hrow = Ph + pix * PSTR;
#pragma unroll
        for (int m = 0; m < 3; ++m) {
            f32x4 a = acc[m][t];
            sh4 hv;
            hv.x = (short)f2bf(fmaxf(a[0], 0.0f));
            hv.y = (short)f2bf(fmaxf(a[1], 0.0f));
            hv.z = (short)f2bf(fmaxf(a[2], 0.0f));
            hv.w = (short)f2bf(fmaxf(a[3], 0.0f));
            *(sh4*)(hrow + 16 * m + 4 * kc) = hv;
        }
    }
    // no barrier: D5 reads the same wave-private rows

    // ---- D5: cur = (w2h+w2l) x H + res; plain scalar stores ----
    {
        const unsigned short* ah = w2h_ + px * 48;
        const unsigned short* al = w2l_ + px * 48;
        bf16x8 A2h1 = lb8(ah + 8 * kc);
        bf16x8 A2h2 = lb8(ah + 32 + 8 * kc);
        bf16x8 A2l1 = lb8(al + 8 * kc);
        bf16x8 A2l2 = lb8(al + 32 + 8 * kc);

        f32x4 q[4];
#pragma unroll
        for (int t = 0; t < 4; ++t) q[t] = 0.0f;
#pragma unroll
        for (int t = 0; t < 4; ++t) {
            const int pix = 64 * wv + 16 * t + px;
            const unsigned short* bh = Ph + pix * PSTR;
            bf16x8 B1 = lb8(bh + 8 * kc);
            bf16x8 B2 = (kc < 2) ? lb8(bh + 32 + 8 * kc) : zero8;
            f32x4 a = q[t];
            a = __builtin_amdgcn_mfma_f32_16x16x32_bf16(A2l1, B1, a, 0, 0, 0);
            a = __builtin_amdgcn_mfma_f32_16x16x32_bf16(A2l2, B2, a, 0, 0, 0);
            a = __builtin_amdgcn_mfma_f32_16x16x32_bf16(A2h1, B1, a, 0, 0, 0);
            a = __builtin_amdgcn_mfma_f32_16x16x32_bf16(A2h2, B2, a, 0, 0, 0);
            q[t] = a;
        }

        float* ob = cout + (size_t)n * CH * HWSZ;
#pragma unroll
        for (int t = 0; t < 4; ++t) {
            const int pix = 64 * wv + 16 * t + px;
            const int rowoff = (by + (pix >> 5)) * WW + bx + (pix & 31);
#pragma unroll
            for (int r = 0; r < 4; ++r)
                ob[(size_t)(4 * kc + r) * HWSZ + rowoff] = q[t][r] + res[t][r];
        }
    }
}

// ---------------- final: apply gate(30), emit channels 1..10 ----------------
__global__ __launch_bounds__(256) void final_kernel(
    const float* __restrict__ cur, const uint8_t* __restrict__ pre,
    float* __restrict__ out) {
    int i = blockIdx.x * 256 + threadIdx.x;        // over NIMG*H*W
    if (i >= NIMG * HWSZ) return;
    int x = i % WW, y = (i / WW) % HH, n = i / HWSZ;
    const float* c0 = cur + (size_t)n * CH * HWSZ;
    float pm = -1e30f;
    for (int dy = -1; dy <= 1; ++dy) {
        int yy = y + dy;
        if ((unsigned)yy >= HH) continue;
        for (int dx = -1; dx <= 1; ++dx) {
            int xx = x + dx;
            if ((unsigned)xx >= WW) continue;
            pm = fmaxf(pm, c0[yy * WW + xx]);
        }
    }
    const bool alive = pre[i] && (pm > THR);
    float* ob = out + (size_t)n * 10 * HWSZ + y * WW + x;
#pragma unroll
    for (int k = 1; k <= 10; ++k)
        ob[(k - 1) * HWSZ] = alive ? c0[k * HWSZ + y * WW + x] : 0.0f;
}

extern "C" void kernel_launch(void* const* d_in, const int* in_sizes, int n_in,
                              void* d_out, int out_size, void* d_ws, size_t ws_size,
                              hipStream_t stream) {
    const float* inp = (const float*)d_in[0];
    const float* w1  = (const float*)d_in[1];
    const float* w2  = (const float*)d_in[2];
    float* out = (float*)d_out;

    const size_t SE = (size_t)NIMG * CH * HWSZ;    // 8,388,608 floats
    float* bufA = (float*)d_ws;
    float* bufB = bufA + SE;
    uint8_t* bitsA = (uint8_t*)(bufB + SE);
    uint8_t* bitsB = bitsA + (size_t)NIMG * HWSZ;
    // weight fragments (bf16), padded +32 shorts so chunk-2 A reads stay in-bounds
    unsigned short* w1h = (unsigned short*)(bitsB + (size_t)NIMG * HWSZ);
    unsigned short* w1l = w1h + (48 * 48 + 32);
    unsigned short* w2h = w1l + (48 * 48 + 32);
    unsigned short* w2l = w2h + (16 * 48 + 32);

    prepack<<<1, 256, 0, stream>>>(w1, w2, w1h, w1l, w2h, w2l);

    const int nblk = NIMG * (HH / TY) * (WW / TX);   // 2048, 1-D swizzled grid
    float* src = bufB;      // dummy on first iter (first=1 reads inp)
    float* dst = bufA;
    uint8_t* pin = bitsB;   // unused on first iter (gate=0)
    uint8_t* pout = bitsA;
    for (int it = 0; it < NUM_ITER; ++it) {
        step_kernel<<<nblk, 256, 0, stream>>>(inp, src, dst, pin, pout,
                                              w1h, w1l, w2h, w2l,
                                              it == 0 ? 0 : 1, it == 0 ? 1 : 0);
        float* t = src; src = dst; dst = t;
        uint8_t* tb = pin; pin = pout; pout = tb;
    }
    // after loop: src = cur(30), pin = pre(30) bits
    final_kernel<<<(NIMG * HWSZ + 255) / 256, 256, 0, stream>>>(src, pin, out);
}